// Round 1
// baseline (1029.599 us; speedup 1.0000x reference)
//
#include <hip/hip_runtime.h>
#include <hip/hip_bf16.h>

#define SEQ 2048
#define DH 64
#define BHCOUNT 32
#define NROWS (BHCOUNT*SEQ)   /* 65536 rows of [64] */

typedef unsigned short u16;
typedef unsigned int u32;

__device__ __forceinline__ float bf2f(u16 h) {
    return __uint_as_float(((u32)h) << 16);
}
__device__ __forceinline__ u16 f2bf(float f) {
    u32 u = __float_as_uint(f);
    u32 r = (u + 0x7FFFu + ((u >> 16) & 1u)) >> 16;
    return (u16)r;
}

// ---------------------------------------------------------------------------
// Kernel 1: QKV projection.  x[65536][64] fp32 -> Q,K,V bf16 [65536][64]
// y = x @ W^T + b  (torch Linear), W is [64][64] row-major (out, in)
// ---------------------------------------------------------------------------
__global__ __launch_bounds__(256) void qkv_kernel(
    const float* __restrict__ x,
    const float* __restrict__ wq, const float* __restrict__ bq,
    const float* __restrict__ wk, const float* __restrict__ bk,
    const float* __restrict__ wv, const float* __restrict__ bv,
    u16* __restrict__ Q, u16* __restrict__ K, u16* __restrict__ V)
{
    __shared__ float wqs[64*68], wks[64*68], wvs[64*68];
    __shared__ float xs[64*64];
    __shared__ float bqs[64], bks[64], bvs[64];
    const int t = threadIdx.x;

    for (int i = t*4; i < 4096; i += 1024) {
        int r = i >> 6, c = i & 63;
        *(float4*)&wqs[r*68+c] = *(const float4*)&wq[i];
        *(float4*)&wks[r*68+c] = *(const float4*)&wk[i];
        *(float4*)&wvs[r*68+c] = *(const float4*)&wv[i];
        *(float4*)&xs[i] = *(const float4*)&x[(size_t)blockIdx.x*4096 + i];
    }
    if (t < 64) { bqs[t] = bq[t]; bks[t] = bk[t]; bvs[t] = bv[t]; }
    __syncthreads();

    const int e = t & 63, wg = t >> 6;
    #pragma unroll
    for (int g = 0; g < 2; ++g) {
        const int r0 = wg*16 + g*8;
        float aq[8], ak[8], av[8];
        #pragma unroll
        for (int i = 0; i < 8; ++i) { aq[i] = bqs[e]; ak[i] = bks[e]; av[i] = bvs[e]; }
        for (int ds = 0; ds < 16; ++ds) {
            float4 q4 = *(const float4*)&wqs[e*68 + ds*4];
            float4 k4 = *(const float4*)&wks[e*68 + ds*4];
            float4 v4 = *(const float4*)&wvs[e*68 + ds*4];
            #pragma unroll
            for (int i = 0; i < 8; ++i) {
                float4 xv = *(const float4*)&xs[(r0+i)*64 + ds*4];
                aq[i] += xv.x*q4.x + xv.y*q4.y + xv.z*q4.z + xv.w*q4.w;
                ak[i] += xv.x*k4.x + xv.y*k4.y + xv.z*k4.z + xv.w*k4.w;
                av[i] += xv.x*v4.x + xv.y*v4.y + xv.z*v4.z + xv.w*v4.w;
            }
        }
        #pragma unroll
        for (int i = 0; i < 8; ++i) {
            size_t row = (size_t)blockIdx.x*64 + r0 + i;
            Q[row*64 + e] = f2bf(aq[i]);
            K[row*64 + e] = f2bf(ak[i]);
            V[row*64 + e] = f2bf(av[i]);
        }
    }
}

// ---------------------------------------------------------------------------
// Kernel 2: flash attention, fp32 compute from bf16 Q/K/V.
// grid (32 qblocks, 32 bh); block 256 = 16 q-groups x 16 k/d-groups.
// Thread (tq,tk): queries 4*tq+i; score keys k = tk+16*j; acc dims d = 4*tk+j.
// ---------------------------------------------------------------------------
__global__ __launch_bounds__(256) void attn_kernel(
    const u16* __restrict__ Q, const u16* __restrict__ K,
    const u16* __restrict__ V, u16* __restrict__ ctx)
{
    __shared__ float Qs[64*68], Ks[64*68], Vs[64*68], Ps[64*68];
    const int t = threadIdx.x;
    const int tq = t >> 4, tk = t & 15;
    const size_t base = (size_t)blockIdx.y * (SEQ*64);
    const size_t qoff = base + (size_t)blockIdx.x * (64*64);

    // stage Q tile (pre-scaled by 1/sqrt(64))
    for (int i = t*4; i < 4096; i += 1024) {
        ushort4 u = *(const ushort4*)&Q[qoff + i];
        int r = i >> 6, c = i & 63;
        float4 f;
        f.x = bf2f(u.x)*0.125f; f.y = bf2f(u.y)*0.125f;
        f.z = bf2f(u.z)*0.125f; f.w = bf2f(u.w)*0.125f;
        *(float4*)&Qs[r*68+c] = f;
    }

    float m[4], l[4], acc[4][4];
    #pragma unroll
    for (int i = 0; i < 4; ++i) {
        m[i] = -1e30f; l[i] = 0.f;
        #pragma unroll
        for (int j = 0; j < 4; ++j) acc[i][j] = 0.f;
    }

    for (int kt = 0; kt < 32; ++kt) {
        const size_t koff = base + (size_t)kt * (64*64);
        __syncthreads();   // previous tile's reads (and Qs stage on kt=0) done
        for (int i = t*4; i < 4096; i += 1024) {
            int r = i >> 6, c = i & 63;
            ushort4 uk = *(const ushort4*)&K[koff + i];
            ushort4 uv = *(const ushort4*)&V[koff + i];
            float4 fk, fv;
            fk.x = bf2f(uk.x); fk.y = bf2f(uk.y); fk.z = bf2f(uk.z); fk.w = bf2f(uk.w);
            fv.x = bf2f(uv.x); fv.y = bf2f(uv.y); fv.z = bf2f(uv.z); fv.w = bf2f(uv.w);
            *(float4*)&Ks[r*68+c] = fk;
            *(float4*)&Vs[r*68+c] = fv;
        }
        __syncthreads();

        // scores S[q][k], q = 4tq+i, k = tk+16j
        float s[4][4];
        #pragma unroll
        for (int i = 0; i < 4; ++i)
            #pragma unroll
            for (int j = 0; j < 4; ++j) s[i][j] = 0.f;
        for (int ds = 0; ds < 16; ++ds) {
            float4 q4[4], k4[4];
            #pragma unroll
            for (int i = 0; i < 4; ++i) q4[i] = *(const float4*)&Qs[(4*tq+i)*68 + ds*4];
            #pragma unroll
            for (int j = 0; j < 4; ++j) k4[j] = *(const float4*)&Ks[(tk+16*j)*68 + ds*4];
            #pragma unroll
            for (int i = 0; i < 4; ++i)
                #pragma unroll
                for (int j = 0; j < 4; ++j)
                    s[i][j] += q4[i].x*k4[j].x + q4[i].y*k4[j].y
                             + q4[i].z*k4[j].z + q4[i].w*k4[j].w;
        }

        // online softmax (reduce over the 16 lanes sharing tq)
        float p[4][4];
        #pragma unroll
        for (int i = 0; i < 4; ++i) {
            float mt = fmaxf(fmaxf(s[i][0], s[i][1]), fmaxf(s[i][2], s[i][3]));
            mt = fmaxf(mt, __shfl_xor(mt, 1));
            mt = fmaxf(mt, __shfl_xor(mt, 2));
            mt = fmaxf(mt, __shfl_xor(mt, 4));
            mt = fmaxf(mt, __shfl_xor(mt, 8));
            float mn = fmaxf(m[i], mt);
            float alpha = __expf(m[i] - mn);
            m[i] = mn;
            float rs = 0.f;
            #pragma unroll
            for (int j = 0; j < 4; ++j) { p[i][j] = __expf(s[i][j] - mn); rs += p[i][j]; }
            rs += __shfl_xor(rs, 1);
            rs += __shfl_xor(rs, 2);
            rs += __shfl_xor(rs, 4);
            rs += __shfl_xor(rs, 8);
            l[i] = l[i]*alpha + rs;
            #pragma unroll
            for (int j = 0; j < 4; ++j) acc[i][j] *= alpha;
            #pragma unroll
            for (int j = 0; j < 4; ++j) Ps[(4*tq+i)*68 + tk + 16*j] = p[i][j];
        }
        __syncthreads();

        // PV: acc[q][d] += sum_k P[q][k] * V[k][d],  d = 4tk+j
        for (int ks = 0; ks < 16; ++ks) {
            float4 pv[4], vv[4];
            #pragma unroll
            for (int i = 0; i < 4; ++i) pv[i] = *(const float4*)&Ps[(4*tq+i)*68 + ks*4];
            #pragma unroll
            for (int kk = 0; kk < 4; ++kk) vv[kk] = *(const float4*)&Vs[(ks*4+kk)*68 + 4*tk];
            #pragma unroll
            for (int i = 0; i < 4; ++i) {
                acc[i][0] += pv[i].x*vv[0].x + pv[i].y*vv[1].x + pv[i].z*vv[2].x + pv[i].w*vv[3].x;
                acc[i][1] += pv[i].x*vv[0].y + pv[i].y*vv[1].y + pv[i].z*vv[2].y + pv[i].w*vv[3].y;
                acc[i][2] += pv[i].x*vv[0].z + pv[i].y*vv[1].z + pv[i].z*vv[2].z + pv[i].w*vv[3].z;
                acc[i][3] += pv[i].x*vv[0].w + pv[i].y*vv[1].w + pv[i].z*vv[2].w + pv[i].w*vv[3].w;
            }
        }
    }

    #pragma unroll
    for (int i = 0; i < 4; ++i) {
        float inv = 1.f / l[i];
        ushort4 o;
        o.x = f2bf(acc[i][0]*inv); o.y = f2bf(acc[i][1]*inv);
        o.z = f2bf(acc[i][2]*inv); o.w = f2bf(acc[i][3]*inv);
        *(ushort4*)&ctx[qoff + (size_t)(4*tq+i)*64 + 4*tk] = o;
    }
}

// ---------------------------------------------------------------------------
// Kernel 3: output projection. out[4096][1024] = ctx[4096][1024] @ wo^T + bo
// grid (64 rowblocks, 16 colblocks); 64x64 tile, K staged in 16 x 64 chunks.
// ---------------------------------------------------------------------------
__global__ __launch_bounds__(256) void oproj_kernel(
    const u16* __restrict__ ctx, const float* __restrict__ wo,
    const float* __restrict__ bo, float* __restrict__ out)
{
    __shared__ float As[64*68], Bs[64*68];
    const int t = threadIdx.x;
    const int tr = t >> 4, tc = t & 15;
    const int rb = blockIdx.x, cb = blockIdx.y;
    float acc[4][4];
    #pragma unroll
    for (int i = 0; i < 4; ++i)
        #pragma unroll
        for (int j = 0; j < 4; ++j) acc[i][j] = 0.f;

    for (int kt = 0; kt < 16; ++kt) {
        __syncthreads();
        for (int i = t*4; i < 4096; i += 1024) {
            int r = i >> 6, c = i & 63;
            ushort4 u = *(const ushort4*)&ctx[(size_t)(rb*64+r)*1024 + kt*64 + c];
            float4 f;
            f.x = bf2f(u.x); f.y = bf2f(u.y); f.z = bf2f(u.z); f.w = bf2f(u.w);
            *(float4*)&As[r*68+c] = f;
            *(float4*)&Bs[r*68+c] = *(const float4*)&wo[(size_t)(cb*64+r)*1024 + kt*64 + c];
        }
        __syncthreads();
        for (int ds = 0; ds < 16; ++ds) {
            float4 a4[4], b4[4];
            #pragma unroll
            for (int i = 0; i < 4; ++i) a4[i] = *(const float4*)&As[(4*tr+i)*68 + ds*4];
            #pragma unroll
            for (int j = 0; j < 4; ++j) b4[j] = *(const float4*)&Bs[(tc+16*j)*68 + ds*4];
            #pragma unroll
            for (int i = 0; i < 4; ++i)
                #pragma unroll
                for (int j = 0; j < 4; ++j)
                    acc[i][j] += a4[i].x*b4[j].x + a4[i].y*b4[j].y
                               + a4[i].z*b4[j].z + a4[i].w*b4[j].w;
        }
    }

    #pragma unroll
    for (int i = 0; i < 4; ++i)
        #pragma unroll
        for (int j = 0; j < 4; ++j) {
            int row = rb*64 + 4*tr + i;
            int col = cb*64 + tc + 16*j;
            out[(size_t)row*1024 + col] = acc[i][j] + bo[col];
        }
}

extern "C" void kernel_launch(void* const* d_in, const int* in_sizes, int n_in,
                              void* d_out, int out_size, void* d_ws, size_t ws_size,
                              hipStream_t stream) {
    (void)in_sizes; (void)n_in; (void)out_size; (void)ws_size;
    const float* x  = (const float*)d_in[0];
    const float* wq = (const float*)d_in[1];
    const float* bq = (const float*)d_in[2];
    const float* wk = (const float*)d_in[3];
    const float* bk = (const float*)d_in[4];
    const float* wv = (const float*)d_in[5];
    const float* bv = (const float*)d_in[6];
    const float* wo = (const float*)d_in[7];
    const float* bo = (const float*)d_in[8];
    float* out = (float*)d_out;

    // workspace: Q,K,V,ctx as bf16 [65536][64]  -> 4 * 8 MB = 32 MB
    u16* Qb  = (u16*)d_ws;
    u16* Kb  = Qb + (size_t)NROWS*64;
    u16* Vb  = Kb + (size_t)NROWS*64;
    u16* ctx = Vb + (size_t)NROWS*64;

    qkv_kernel<<<dim3(NROWS/64), 256, 0, stream>>>(x, wq, bq, wk, bk, wv, bv, Qb, Kb, Vb);
    attn_kernel<<<dim3(32, 32), 256, 0, stream>>>(Qb, Kb, Vb, ctx);
    oproj_kernel<<<dim3(64, 16), 256, 0, stream>>>(ctx, wo, bo, out);
}

// Round 2
// 297.549 us; speedup vs baseline: 3.4603x; 3.4603x over previous
//
#include <hip/hip_runtime.h>
#include <hip/hip_bf16.h>

#define SEQ 2048
#define BHCOUNT 32
#define NROWS (BHCOUNT*SEQ)   /* 65536 rows of [64] */

typedef unsigned short u16;
typedef unsigned int u32;
using bf16x8 = __attribute__((ext_vector_type(8))) short;   // 8 bf16 = 4 VGPR
using f32x4  = __attribute__((ext_vector_type(4))) float;

__device__ __forceinline__ float bf2f(u16 h) {
    return __uint_as_float(((u32)h) << 16);
}
__device__ __forceinline__ u16 f2bf(float f) {
    u32 u = __float_as_uint(f);
    u32 r = (u + 0x7FFFu + ((u >> 16) & 1u)) >> 16;
    return (u16)r;
}

// ---------------------------------------------------------------------------
// Kernel 1: QKV projection.  x[65536][64] fp32 ->
//   Q bf16 [65536][64]  (pre-scaled by 0.125*log2e for exp2-domain softmax)
//   K bf16 [65536][64]
//   Vt bf16 [32 bh][64 d][2048 s]   (transposed per head for PV B-fragments)
// ---------------------------------------------------------------------------
__global__ __launch_bounds__(256) void qkv_kernel(
    const float* __restrict__ x,
    const float* __restrict__ wq, const float* __restrict__ bq,
    const float* __restrict__ wk, const float* __restrict__ bk,
    const float* __restrict__ wv, const float* __restrict__ bv,
    u16* __restrict__ Q, u16* __restrict__ K, u16* __restrict__ Vt)
{
    __shared__ float wqs[64*68], wks[64*68], wvs[64*68];
    __shared__ float xs[64*64];
    __shared__ float bqs[64], bks[64], bvs[64];
    const int t = threadIdx.x;

    for (int i = t*4; i < 4096; i += 1024) {
        int r = i >> 6, c = i & 63;
        *(float4*)&wqs[r*68+c] = *(const float4*)&wq[i];
        *(float4*)&wks[r*68+c] = *(const float4*)&wk[i];
        *(float4*)&wvs[r*68+c] = *(const float4*)&wv[i];
        *(float4*)&xs[i] = *(const float4*)&x[(size_t)blockIdx.x*4096 + i];
    }
    if (t < 64) { bqs[t] = bq[t]; bks[t] = bk[t]; bvs[t] = bv[t]; }
    __syncthreads();

    const int e = t & 63, wg = t >> 6;
    const int bh = blockIdx.x >> 5;          // 64 rows/block, 32 blocks per bh
    const int s0 = (blockIdx.x & 31) * 64;
    const float qscale = 0.125f * 1.44269504f;
    float va[16];

    #pragma unroll
    for (int g = 0; g < 2; ++g) {
        const int r0 = wg*16 + g*8;
        float aq[8], ak[8], av[8];
        #pragma unroll
        for (int i = 0; i < 8; ++i) { aq[i] = bqs[e]; ak[i] = bks[e]; av[i] = bvs[e]; }
        for (int ds = 0; ds < 16; ++ds) {
            float4 q4 = *(const float4*)&wqs[e*68 + ds*4];
            float4 k4 = *(const float4*)&wks[e*68 + ds*4];
            float4 v4 = *(const float4*)&wvs[e*68 + ds*4];
            #pragma unroll
            for (int i = 0; i < 8; ++i) {
                float4 xv = *(const float4*)&xs[(r0+i)*64 + ds*4];
                aq[i] += xv.x*q4.x + xv.y*q4.y + xv.z*q4.z + xv.w*q4.w;
                ak[i] += xv.x*k4.x + xv.y*k4.y + xv.z*k4.z + xv.w*k4.w;
                av[i] += xv.x*v4.x + xv.y*v4.y + xv.z*v4.z + xv.w*v4.w;
            }
        }
        #pragma unroll
        for (int i = 0; i < 8; ++i) {
            size_t row = (size_t)blockIdx.x*64 + r0 + i;
            Q[row*64 + e] = f2bf(aq[i]*qscale);
            K[row*64 + e] = f2bf(ak[i]);
            va[g*8+i] = av[i];
        }
    }

    // transpose V through xs (rotated layout keeps LDS banks conflict-free)
    __syncthreads();
    #pragma unroll
    for (int g = 0; g < 2; ++g)
        #pragma unroll
        for (int i = 0; i < 8; ++i) {
            int r = wg*16 + g*8 + i;
            xs[e*64 + ((r + e) & 63)] = va[g*8+i];
        }
    __syncthreads();
    const size_t vtbase = (size_t)bh * 64 * SEQ;
    for (int idx = t; idx < 4096; idx += 256) {
        int ee = idx >> 6, s = idx & 63;
        Vt[vtbase + (size_t)ee*SEQ + s0 + s] = f2bf(xs[ee*64 + ((s + ee) & 63)]);
    }
}

// ---------------------------------------------------------------------------
// Kernel 2: MFMA flash attention (bf16 in, fp32 acc).
// grid (32 qtiles, 32 bh); 4 waves, each wave owns 16 q-rows.
// kv-tile = 64.  K and Vt tiles staged in LDS with XOR-swizzled 16B slots
// (slot ^= row&7) so all ds_read_b128 fragment loads are conflict-free.
// A/B frags use identical lane->(row,k) fill => robust to k-permutation.
// C/D layout (HW-verified): col = lane&15, row = (lane>>4)*4 + reg.
// ---------------------------------------------------------------------------
__global__ __launch_bounds__(256) void attn_kernel(
    const u16* __restrict__ Q, const u16* __restrict__ K,
    const u16* __restrict__ Vt, u16* __restrict__ ctx)
{
    __shared__ u16 Ks [64*64];       // [kv][d], swizzled
    __shared__ u16 Vts[64*64];       // [d][kv], swizzled
    __shared__ u16 Ps [4*16*64];     // per-wave P tile [q][kv], swizzled

    const int t = threadIdx.x;
    const int wid = t >> 6, lane = t & 63;
    const int ln = lane & 15, g4 = lane >> 4;
    const int bh = blockIdx.y;
    const size_t base   = (size_t)bh * SEQ * 64;
    const size_t vtbase = (size_t)bh * 64 * SEQ;
    const int q0 = blockIdx.x * 64 + wid * 16;

    // Q fragments in registers: lane holds Q[q0+ln][kf*32 + g4*8 + j]
    bf16x8 qf[2];
    #pragma unroll
    for (int kf = 0; kf < 2; ++kf)
        qf[kf] = *(const bf16x8*)&Q[base + (size_t)(q0 + ln)*64 + kf*32 + g4*8];

    f32x4 oacc[4];
    float m[4], l[4];
    #pragma unroll
    for (int i = 0; i < 4; ++i) {
        oacc[i] = (f32x4){0.f, 0.f, 0.f, 0.f};
        m[i] = -1e30f; l[i] = 0.f;
    }

    for (int kt = 0; kt < 32; ++kt) {
        const int kv0 = kt * 64;
        __syncthreads();   // previous tile's LDS reads complete
        #pragma unroll
        for (int c = 0; c < 2; ++c) {
            int s = t + c*256;                 // 512 slots of 16B per tile
            int row = s >> 3, ks = s & 7;
            int phys = row*64 + ((ks ^ (row & 7)) << 3);
            *(uint4*)&Ks [phys] = *(const uint4*)&K [base  + (size_t)(kv0 + row)*64 + ks*8];
            *(uint4*)&Vts[phys] = *(const uint4*)&Vt[vtbase + (size_t)row*SEQ + kv0 + ks*8];
        }
        __syncthreads();

        // S = Q · K^T : 4 col-tiles of 16, K-frag row = kv col
        f32x4 sacc[4];
        #pragma unroll
        for (int nt = 0; nt < 4; ++nt) sacc[nt] = (f32x4){0.f, 0.f, 0.f, 0.f};
        #pragma unroll
        for (int nt = 0; nt < 4; ++nt) {
            #pragma unroll
            for (int kf = 0; kf < 2; ++kf) {
                int krow = nt*16 + ln;
                bf16x8 kfr = *(const bf16x8*)&Ks[krow*64 + (((kf*4 + g4) ^ (krow & 7)) << 3)];
                sacc[nt] = __builtin_amdgcn_mfma_f32_16x16x32_bf16(qf[kf], kfr, sacc[nt], 0, 0, 0);
            }
        }

        // online softmax (exp2 domain; Q pre-scaled). Row r state in reg r.
        #pragma unroll
        for (int r = 0; r < 4; ++r) {
            float a = fmaxf(fmaxf(sacc[0][r], sacc[1][r]), fmaxf(sacc[2][r], sacc[3][r]));
            a = fmaxf(a, __shfl_xor(a, 1));
            a = fmaxf(a, __shfl_xor(a, 2));
            a = fmaxf(a, __shfl_xor(a, 4));
            a = fmaxf(a, __shfl_xor(a, 8));
            float mn = fmaxf(m[r], a);
            float alpha = exp2f(m[r] - mn);
            m[r] = mn;
            float rs = 0.f;
            const int prow = g4*4 + r;
            #pragma unroll
            for (int nt = 0; nt < 4; ++nt) {
                float p = exp2f(sacc[nt][r] - mn);
                rs += p;
                int pcol = ln + 16*nt;
                Ps[wid*1024 + prow*64 + (((pcol >> 3) ^ (prow & 7)) << 3) + (pcol & 7)] = f2bf(p);
            }
            rs += __shfl_xor(rs, 1);
            rs += __shfl_xor(rs, 2);
            rs += __shfl_xor(rs, 4);
            rs += __shfl_xor(rs, 8);
            l[r] = l[r]*alpha + rs;
            #pragma unroll
            for (int dt = 0; dt < 4; ++dt) oacc[dt][r] *= alpha;
        }

        // O += P · V : P A-frags (per-wave LDS), V B-frags (Vts)
        bf16x8 pf[2];
        #pragma unroll
        for (int kf = 0; kf < 2; ++kf)
            pf[kf] = *(const bf16x8*)&Ps[wid*1024 + ln*64 + (((kf*4 + g4) ^ (ln & 7)) << 3)];
        #pragma unroll
        for (int dt = 0; dt < 4; ++dt) {
            #pragma unroll
            for (int kf = 0; kf < 2; ++kf) {
                int vrow = dt*16 + ln;
                bf16x8 vfr = *(const bf16x8*)&Vts[vrow*64 + (((kf*4 + g4) ^ (vrow & 7)) << 3)];
                oacc[dt] = __builtin_amdgcn_mfma_f32_16x16x32_bf16(pf[kf], vfr, oacc[dt], 0, 0, 0);
            }
        }
    }

    // epilogue: normalize and store ctx (row-major [row][64])
    #pragma unroll
    for (int r = 0; r < 4; ++r) {
        float inv = 1.f / l[r];
        size_t row = base + (size_t)(q0 + g4*4 + r)*64;
        #pragma unroll
        for (int dt = 0; dt < 4; ++dt)
            ctx[row + dt*16 + ln] = f2bf(oacc[dt][r] * inv);
    }
}

// ---------------------------------------------------------------------------
// Kernel 3: output projection. out[4096][1024] = ctx[4096][1024] @ wo^T + bo
// ---------------------------------------------------------------------------
__global__ __launch_bounds__(256) void oproj_kernel(
    const u16* __restrict__ ctx, const float* __restrict__ wo,
    const float* __restrict__ bo, float* __restrict__ out)
{
    __shared__ float As[64*68], Bs[64*68];
    const int t = threadIdx.x;
    const int tr = t >> 4, tc = t & 15;
    const int rb = blockIdx.x, cb = blockIdx.y;
    float acc[4][4];
    #pragma unroll
    for (int i = 0; i < 4; ++i)
        #pragma unroll
        for (int j = 0; j < 4; ++j) acc[i][j] = 0.f;

    for (int kt = 0; kt < 16; ++kt) {
        __syncthreads();
        for (int i = t*4; i < 4096; i += 1024) {
            int r = i >> 6, c = i & 63;
            ushort4 u = *(const ushort4*)&ctx[(size_t)(rb*64+r)*1024 + kt*64 + c];
            float4 f;
            f.x = bf2f(u.x); f.y = bf2f(u.y); f.z = bf2f(u.z); f.w = bf2f(u.w);
            *(float4*)&As[r*68+c] = f;
            *(float4*)&Bs[r*68+c] = *(const float4*)&wo[(size_t)(cb*64+r)*1024 + kt*64 + c];
        }
        __syncthreads();
        for (int ds = 0; ds < 16; ++ds) {
            float4 a4[4], b4[4];
            #pragma unroll
            for (int i = 0; i < 4; ++i) a4[i] = *(const float4*)&As[(4*tr+i)*68 + ds*4];
            #pragma unroll
            for (int j = 0; j < 4; ++j) b4[j] = *(const float4*)&Bs[(tc+16*j)*68 + ds*4];
            #pragma unroll
            for (int i = 0; i < 4; ++i)
                #pragma unroll
                for (int j = 0; j < 4; ++j)
                    acc[i][j] += a4[i].x*b4[j].x + a4[i].y*b4[j].y
                               + a4[i].z*b4[j].z + a4[i].w*b4[j].w;
        }
    }

    #pragma unroll
    for (int i = 0; i < 4; ++i)
        #pragma unroll
        for (int j = 0; j < 4; ++j) {
            int row = rb*64 + 4*tr + i;
            int col = cb*64 + tc + 16*j;
            out[(size_t)row*1024 + col] = acc[i][j] + bo[col];
        }
}

extern "C" void kernel_launch(void* const* d_in, const int* in_sizes, int n_in,
                              void* d_out, int out_size, void* d_ws, size_t ws_size,
                              hipStream_t stream) {
    (void)in_sizes; (void)n_in; (void)out_size; (void)ws_size;
    const float* x  = (const float*)d_in[0];
    const float* wq = (const float*)d_in[1];
    const float* bq = (const float*)d_in[2];
    const float* wk = (const float*)d_in[3];
    const float* bk = (const float*)d_in[4];
    const float* wv = (const float*)d_in[5];
    const float* bv = (const float*)d_in[6];
    const float* wo = (const float*)d_in[7];
    const float* bo = (const float*)d_in[8];
    float* out = (float*)d_out;

    // workspace: Q,K bf16 [65536][64]; Vt bf16 [32][64][2048]; ctx bf16 -> 32 MB
    u16* Qb  = (u16*)d_ws;
    u16* Kb  = Qb + (size_t)NROWS*64;
    u16* Vtb = Kb + (size_t)NROWS*64;
    u16* ctx = Vtb + (size_t)NROWS*64;

    qkv_kernel<<<dim3(NROWS/64), 256, 0, stream>>>(x, wq, bq, wk, bk, wv, bv, Qb, Kb, Vtb);
    attn_kernel<<<dim3(32, 32), 256, 0, stream>>>(Qb, Kb, Vtb, ctx);
    oproj_kernel<<<dim3(64, 16), 256, 0, stream>>>(ctx, wo, bo, out);
}